// Round 1
// baseline (333.718 us; speedup 1.0000x reference)
//
#include <hip/hip_runtime.h>
#include <hip/hip_bf16.h>

#define B_  4
#define N_  512
#define D_  128
#define H_  8
#define DK  16
#define DFF 512
#define NB  32

// ---------------- generic tiled fp32 GEMM ----------------
// C = A[M,K] @ B[K,N] (+bias) (+resid) (relu optional). blockIdx.z selects B/C
// pointer pair (used to fuse the Q/K/V projections into one launch).
#define BM 64
#define BN 64
#define BKK 16

__global__ __launch_bounds__(256) void gemm_kernel(
    const float* __restrict__ A,
    const float* __restrict__ B0, const float* __restrict__ B1, const float* __restrict__ B2,
    float* __restrict__ C0, float* __restrict__ C1, float* __restrict__ C2,
    const float* __restrict__ bias, const float* __restrict__ resid,
    int M, int N, int K, int relu)
{
    const float* Bm = blockIdx.z == 0 ? B0 : (blockIdx.z == 1 ? B1 : B2);
    float*       C  = blockIdx.z == 0 ? C0 : (blockIdx.z == 1 ? C1 : C2);

    __shared__ float As[BM][BKK + 1];
    __shared__ float Bs[BKK][BN];

    const int tid = threadIdx.x;
    const int tx = tid & 15, ty = tid >> 4;
    const int bn = blockIdx.x * BN;
    const int bmrow = blockIdx.y * BM;

    const int ar = tid >> 2, ac = (tid & 3) << 2;   // A tile: 64 rows x 16 cols
    const int br = tid >> 4, bc = (tid & 15) << 2;  // B tile: 16 rows x 64 cols

    float acc[4][4] = {};

    for (int k0 = 0; k0 < K; k0 += BKK) {
        float4 av = *(const float4*)&A[(size_t)(bmrow + ar) * K + k0 + ac];
        As[ar][ac + 0] = av.x; As[ar][ac + 1] = av.y;
        As[ar][ac + 2] = av.z; As[ar][ac + 3] = av.w;
        float4 bv = *(const float4*)&Bm[(size_t)(k0 + br) * N + bn + bc];
        *(float4*)&Bs[br][bc] = bv;
        __syncthreads();
#pragma unroll
        for (int kk = 0; kk < BKK; ++kk) {
            float a0 = As[ty * 4 + 0][kk];
            float a1 = As[ty * 4 + 1][kk];
            float a2 = As[ty * 4 + 2][kk];
            float a3 = As[ty * 4 + 3][kk];
            float4 b = *(float4*)&Bs[kk][tx * 4];
            acc[0][0] += a0 * b.x; acc[0][1] += a0 * b.y; acc[0][2] += a0 * b.z; acc[0][3] += a0 * b.w;
            acc[1][0] += a1 * b.x; acc[1][1] += a1 * b.y; acc[1][2] += a1 * b.z; acc[1][3] += a1 * b.w;
            acc[2][0] += a2 * b.x; acc[2][1] += a2 * b.y; acc[2][2] += a2 * b.z; acc[2][3] += a2 * b.w;
            acc[3][0] += a3 * b.x; acc[3][1] += a3 * b.y; acc[3][2] += a3 * b.z; acc[3][3] += a3 * b.w;
        }
        __syncthreads();
    }

    float4 bb = make_float4(0.f, 0.f, 0.f, 0.f);
    if (bias) bb = *(const float4*)&bias[bn + tx * 4];
#pragma unroll
    for (int i = 0; i < 4; ++i) {
        int row = bmrow + ty * 4 + i;
        float4 r;
        r.x = acc[i][0] + bb.x; r.y = acc[i][1] + bb.y;
        r.z = acc[i][2] + bb.z; r.w = acc[i][3] + bb.w;
        if (resid) {
            float4 rv = *(const float4*)&resid[(size_t)row * N + bn + tx * 4];
            r.x += rv.x; r.y += rv.y; r.z += rv.z; r.w += rv.w;
        }
        if (relu) {
            r.x = fmaxf(r.x, 0.f); r.y = fmaxf(r.y, 0.f);
            r.z = fmaxf(r.z, 0.f); r.w = fmaxf(r.w, 0.f);
        }
        *(float4*)&C[(size_t)row * N + bn + tx * 4] = r;
    }
}

// ---------------- QE precompute: QE[row,h,k] = Q[row,h,:] . emb[k,h,:] ----------------
__global__ __launch_bounds__(256) void qe_kernel(const float* __restrict__ Q,
                                                 const float* __restrict__ emb,
                                                 float* __restrict__ QE)
{
    int idx = blockIdx.x * 256 + threadIdx.x;   // [0, R*H*NB)
    int k   = idx & (NB - 1);
    int hh  = (idx >> 5) & (H_ - 1);
    int row = idx >> 8;
    const float4* qp = (const float4*)(Q + (size_t)row * D_ + hh * DK);
    const float4* ep = (const float4*)(emb + (size_t)k * D_ + hh * DK);
    float4 q0 = qp[0], q1 = qp[1], q2 = qp[2], q3 = qp[3];
    float4 e0 = ep[0], e1 = ep[1], e2 = ep[2], e3 = ep[3];
    float dot = q0.x*e0.x + q0.y*e0.y + q0.z*e0.z + q0.w*e0.w
              + q1.x*e1.x + q1.y*e1.y + q1.z*e1.z + q1.w*e1.w
              + q2.x*e2.x + q2.y*e2.y + q2.z*e2.z + q2.w*e2.w
              + q3.x*e3.x + q3.y*e3.y + q3.z*e3.z + q3.w*e3.w;
    QE[idx] = dot;
}

// ---------------- attention: one wave per (b,h,n) row ----------------
__global__ __launch_bounds__(256) void attn_kernel(
    const float* __restrict__ Q, const float* __restrict__ K, const float* __restrict__ V,
    const float* __restrict__ QE, const float* __restrict__ coords,
    float* __restrict__ O)
{
    const int wave = threadIdx.x >> 6;
    const int lane = threadIdx.x & 63;
    const int row = blockIdx.x * 4 + wave;     // [0, B*H*N)
    const int n = row & (N_ - 1);
    const int h = (row >> 9) & (H_ - 1);
    const int b = row >> 12;

    const float4* qp = (const float4*)(Q + ((size_t)(b * N_ + n) * D_ + h * DK));
    const float4 q0 = qp[0], q1 = qp[1], q2 = qp[2], q3 = qp[3];
    const float cx = coords[(size_t)(b * N_ + n) * 2 + 0];
    const float cy = coords[(size_t)(b * N_ + n) * 2 + 1];
    const float qe = (lane < NB) ? QE[((size_t)(b * N_ + n) * H_ + h) * NB + lane] : 0.f;

    float s[8];
#pragma unroll
    for (int i = 0; i < 8; ++i) {
        int m = i * 64 + lane;
        const float4* kp = (const float4*)(K + ((size_t)(b * N_ + m) * D_ + h * DK));
        float4 k0 = kp[0], k1 = kp[1], k2 = kp[2], k3 = kp[3];
        float dot = q0.x*k0.x + q0.y*k0.y + q0.z*k0.z + q0.w*k0.w
                  + q1.x*k1.x + q1.y*k1.y + q1.z*k1.z + q1.w*k1.w
                  + q2.x*k2.x + q2.y*k2.y + q2.z*k2.z + q2.w*k2.w
                  + q3.x*k3.x + q3.y*k3.y + q3.z*k3.z + q3.w*k3.w;
        float2 cm = *(const float2*)&coords[(size_t)(b * N_ + m) * 2];
        float dx = cx - cm.x, dy = cy - cm.y;
        float dist = sqrtf(dx * dx + dy * dy);
        int bucket = (int)(dist * 32.0f);
        bucket = bucket > (NB - 1) ? (NB - 1) : bucket;
        s[i] = dot * 0.25f + __shfl(qe, bucket, 64);
    }

    // row max
    float mx = s[0];
#pragma unroll
    for (int i = 1; i < 8; ++i) mx = fmaxf(mx, s[i]);
#pragma unroll
    for (int off = 32; off >= 1; off >>= 1) mx = fmaxf(mx, __shfl_xor(mx, off, 64));

    float p[8];
    float l = 0.f;
#pragma unroll
    for (int i = 0; i < 8; ++i) { p[i] = __expf(s[i] - mx); l += p[i]; }

    float acc[16] = {};
#pragma unroll
    for (int i = 0; i < 8; ++i) {
        int m = i * 64 + lane;
        const float4* vp = (const float4*)(V + ((size_t)(b * N_ + m) * D_ + h * DK));
        float4 v0 = vp[0], v1 = vp[1], v2 = vp[2], v3 = vp[3];
        float pi = p[i];
        acc[0] += pi * v0.x;  acc[1] += pi * v0.y;  acc[2] += pi * v0.z;  acc[3] += pi * v0.w;
        acc[4] += pi * v1.x;  acc[5] += pi * v1.y;  acc[6] += pi * v1.z;  acc[7] += pi * v1.w;
        acc[8] += pi * v2.x;  acc[9] += pi * v2.y;  acc[10] += pi * v2.z; acc[11] += pi * v2.w;
        acc[12] += pi * v3.x; acc[13] += pi * v3.y; acc[14] += pi * v3.z; acc[15] += pi * v3.w;
    }

#pragma unroll
    for (int off = 32; off >= 1; off >>= 1) {
        l += __shfl_xor(l, off, 64);
#pragma unroll
        for (int d = 0; d < 16; ++d) acc[d] += __shfl_xor(acc[d], off, 64);
    }

    if (lane == 0) {
        float inv = 1.0f / l;
        float* op = O + ((size_t)(b * N_ + n) * D_ + h * DK);
        float4 o0 = make_float4(acc[0]*inv,  acc[1]*inv,  acc[2]*inv,  acc[3]*inv);
        float4 o1 = make_float4(acc[4]*inv,  acc[5]*inv,  acc[6]*inv,  acc[7]*inv);
        float4 o2 = make_float4(acc[8]*inv,  acc[9]*inv,  acc[10]*inv, acc[11]*inv);
        float4 o3 = make_float4(acc[12]*inv, acc[13]*inv, acc[14]*inv, acc[15]*inv);
        ((float4*)op)[0] = o0; ((float4*)op)[1] = o1;
        ((float4*)op)[2] = o2; ((float4*)op)[3] = o3;
    }
}

// ---------------- instance norm over N per (b,d) ----------------
__global__ __launch_bounds__(512) void inorm_kernel(const float* __restrict__ X,
                                                    const float* __restrict__ gamma,
                                                    const float* __restrict__ beta,
                                                    float* __restrict__ Y)
{
    const int b = blockIdx.x;
    const int t = threadIdx.x;
    const int d = t & (D_ - 1);
    const int s = t >> 7;                       // 0..3 strip over N
    const float* xb = X + (size_t)b * N_ * D_;

    float sum = 0.f, sq = 0.f;
    for (int n = s * 128; n < s * 128 + 128; ++n) {
        float x = xb[(size_t)n * D_ + d];
        sum += x; sq += x * x;
    }
    __shared__ float ls[4][D_], lq[4][D_];
    __shared__ float lm[D_], lr[D_];
    ls[s][d] = sum; lq[s][d] = sq;
    __syncthreads();
    if (s == 0) {
        float S = ls[0][d] + ls[1][d] + ls[2][d] + ls[3][d];
        float Q2 = lq[0][d] + lq[1][d] + lq[2][d] + lq[3][d];
        float mean = S * (1.0f / N_);
        float var = Q2 * (1.0f / N_) - mean * mean;
        lm[d] = mean;
        lr[d] = 1.0f / sqrtf(var + 1e-5f);
    }
    __syncthreads();
    const float mean = lm[d], rstd = lr[d], g = gamma[d], be = beta[d];
    float* yb = Y + (size_t)b * N_ * D_;
    for (int n = s * 128; n < s * 128 + 128; ++n) {
        float x = xb[(size_t)n * D_ + d];
        yb[(size_t)n * D_ + d] = (x - mean) * rstd * g + be;
    }
}

extern "C" void kernel_launch(void* const* d_in, const int* in_sizes, int n_in,
                              void* d_out, int out_size, void* d_ws, size_t ws_size,
                              hipStream_t stream)
{
    const float* h      = (const float*)d_in[0];
    const float* coords = (const float*)d_in[1];
    const float* W_Q    = (const float*)d_in[2];
    const float* W_K    = (const float*)d_in[3];
    const float* W_V    = (const float*)d_in[4];
    const float* W_O    = (const float*)d_in[5];
    const float* emb    = (const float*)d_in[6];
    const float* w1     = (const float*)d_in[7];
    const float* b1     = (const float*)d_in[8];
    const float* w2     = (const float*)d_in[9];
    const float* b2     = (const float*)d_in[10];
    const float* g1     = (const float*)d_in[11];
    const float* be1    = (const float*)d_in[12];
    const float* g2     = (const float*)d_in[13];
    const float* be2    = (const float*)d_in[14];
    float* out = (float*)d_out;

    float* ws = (float*)d_ws;
    const size_t R = (size_t)B_ * N_;          // 2048 rows
    float* Qb  = ws;
    float* Kb  = Qb + R * D_;
    float* Vb  = Kb + R * D_;
    float* QEb = Vb + R * D_;                  // R * H_ * NB
    float* AO  = QEb + R * H_ * NB;
    float* X1  = AO + R * D_;
    float* H1  = X1 + R * D_;
    float* F1  = H1 + R * D_;                  // R * DFF
    float* X2  = F1 + R * DFF;

    // 1. Q,K,V projections (fused via blockIdx.z)
    gemm_kernel<<<dim3(D_ / BN, R / BM, 3), 256, 0, stream>>>(
        h, W_Q, W_K, W_V, Qb, Kb, Vb, nullptr, nullptr, (int)R, D_, D_, 0);
    // 2. QE table (32-bucket factorization of the relative-position einsum)
    qe_kernel<<<dim3((R * H_ * NB) / 256), 256, 0, stream>>>(Qb, emb, QEb);
    // 3. attention (flash-style, no S matrix)
    attn_kernel<<<dim3((B_ * H_ * N_) / 4), 256, 0, stream>>>(Qb, Kb, Vb, QEb, coords, AO);
    // 4. O-projection + residual h
    gemm_kernel<<<dim3(D_ / BN, R / BM, 1), 256, 0, stream>>>(
        AO, W_O, W_O, W_O, X1, X1, X1, nullptr, h, (int)R, D_, D_, 0);
    // 5. instance norm 1
    inorm_kernel<<<dim3(B_), 512, 0, stream>>>(X1, g1, be1, H1);
    // 6. FFN layer 1 (+bias, relu)
    gemm_kernel<<<dim3(DFF / BN, R / BM, 1), 256, 0, stream>>>(
        H1, w1, w1, w1, F1, F1, F1, b1, nullptr, (int)R, DFF, D_, 1);
    // 7. FFN layer 2 (+bias, +residual h1)
    gemm_kernel<<<dim3(D_ / BN, R / BM, 1), 256, 0, stream>>>(
        F1, w2, w2, w2, X2, X2, X2, b2, H1, (int)R, D_, DFF, 0);
    // 8. instance norm 2 -> output
    inorm_kernel<<<dim3(B_), 512, 0, stream>>>(X2, g2, be2, out);
}

// Round 2
// 250.354 us; speedup vs baseline: 1.3330x; 1.3330x over previous
//
#include <hip/hip_runtime.h>
#include <hip/hip_bf16.h>

#define B_  4
#define N_  512
#define D_  128
#define H_  8
#define DK  16
#define DFF 512
#define NB  32

// ---------------- generic tiled fp32 GEMM ----------------
#define BM 64
#define BN 64
#define BKK 16

__global__ __launch_bounds__(256) void gemm_kernel(
    const float* __restrict__ A,
    const float* __restrict__ B0, const float* __restrict__ B1, const float* __restrict__ B2,
    float* __restrict__ C0, float* __restrict__ C1, float* __restrict__ C2,
    const float* __restrict__ bias, const float* __restrict__ resid,
    int M, int N, int K, int relu)
{
    const float* Bm = blockIdx.z == 0 ? B0 : (blockIdx.z == 1 ? B1 : B2);
    float*       C  = blockIdx.z == 0 ? C0 : (blockIdx.z == 1 ? C1 : C2);

    __shared__ float As[BM][BKK + 1];
    __shared__ float Bs[BKK][BN];

    const int tid = threadIdx.x;
    const int tx = tid & 15, ty = tid >> 4;
    const int bn = blockIdx.x * BN;
    const int bmrow = blockIdx.y * BM;

    const int ar = tid >> 2, ac = (tid & 3) << 2;
    const int br = tid >> 4, bc = (tid & 15) << 2;

    float acc[4][4] = {};

    for (int k0 = 0; k0 < K; k0 += BKK) {
        float4 av = *(const float4*)&A[(size_t)(bmrow + ar) * K + k0 + ac];
        As[ar][ac + 0] = av.x; As[ar][ac + 1] = av.y;
        As[ar][ac + 2] = av.z; As[ar][ac + 3] = av.w;
        float4 bv = *(const float4*)&Bm[(size_t)(k0 + br) * N + bn + bc];
        *(float4*)&Bs[br][bc] = bv;
        __syncthreads();
#pragma unroll
        for (int kk = 0; kk < BKK; ++kk) {
            float a0 = As[ty * 4 + 0][kk];
            float a1 = As[ty * 4 + 1][kk];
            float a2 = As[ty * 4 + 2][kk];
            float a3 = As[ty * 4 + 3][kk];
            float4 b = *(float4*)&Bs[kk][tx * 4];
            acc[0][0] += a0 * b.x; acc[0][1] += a0 * b.y; acc[0][2] += a0 * b.z; acc[0][3] += a0 * b.w;
            acc[1][0] += a1 * b.x; acc[1][1] += a1 * b.y; acc[1][2] += a1 * b.z; acc[1][3] += a1 * b.w;
            acc[2][0] += a2 * b.x; acc[2][1] += a2 * b.y; acc[2][2] += a2 * b.z; acc[2][3] += a2 * b.w;
            acc[3][0] += a3 * b.x; acc[3][1] += a3 * b.y; acc[3][2] += a3 * b.z; acc[3][3] += a3 * b.w;
        }
        __syncthreads();
    }

    float4 bb = make_float4(0.f, 0.f, 0.f, 0.f);
    if (bias) bb = *(const float4*)&bias[bn + tx * 4];
#pragma unroll
    for (int i = 0; i < 4; ++i) {
        int row = bmrow + ty * 4 + i;
        float4 r;
        r.x = acc[i][0] + bb.x; r.y = acc[i][1] + bb.y;
        r.z = acc[i][2] + bb.z; r.w = acc[i][3] + bb.w;
        if (resid) {
            float4 rv = *(const float4*)&resid[(size_t)row * N + bn + tx * 4];
            r.x += rv.x; r.y += rv.y; r.z += rv.z; r.w += rv.w;
        }
        if (relu) {
            r.x = fmaxf(r.x, 0.f); r.y = fmaxf(r.y, 0.f);
            r.z = fmaxf(r.z, 0.f); r.w = fmaxf(r.w, 0.f);
        }
        *(float4*)&C[(size_t)row * N + bn + tx * 4] = r;
    }
}

// ---------------- QE precompute: QE[row,h,k] = Q[row,h,:] . emb[k,h,:] ----------------
__global__ __launch_bounds__(256) void qe_kernel(const float* __restrict__ Q,
                                                 const float* __restrict__ emb,
                                                 float* __restrict__ QE)
{
    int idx = blockIdx.x * 256 + threadIdx.x;   // [0, R*H*NB)
    int k   = idx & (NB - 1);
    int hh  = (idx >> 5) & (H_ - 1);
    int row = idx >> 8;
    const float4* qp = (const float4*)(Q + (size_t)row * D_ + hh * DK);
    const float4* ep = (const float4*)(emb + (size_t)k * D_ + hh * DK);
    float4 q0 = qp[0], q1 = qp[1], q2 = qp[2], q3 = qp[3];
    float4 e0 = ep[0], e1 = ep[1], e2 = ep[2], e3 = ep[3];
    float dot = q0.x*e0.x + q0.y*e0.y + q0.z*e0.z + q0.w*e0.w
              + q1.x*e1.x + q1.y*e1.y + q1.z*e1.z + q1.w*e1.w
              + q2.x*e2.x + q2.y*e2.y + q2.z*e2.z + q2.w*e2.w
              + q3.x*e3.x + q3.y*e3.y + q3.z*e3.z + q3.w*e3.w;
    QE[idx] = dot;
}

// ---------------- attention v2: lane-per-query-row, wave-uniform K/V stream --------
// grid: 256 blocks = (b, h, n-chunk of 64). block = 4 waves; wave w streams keys
// m in [w*128, w*128+128) for all 64 rows (one row per lane). K/V/coords[m] reads
// are wave-uniform -> scalar loads from L2. Softmax without max subtraction
// (|s| <~ 12 << 88), so partial (l, acc) combine linearly across waves in LDS.
__global__ __launch_bounds__(256) void attn2_kernel(
    const float* __restrict__ Q, const float* __restrict__ K, const float* __restrict__ V,
    const float* __restrict__ QE, const float* __restrict__ coords,
    float* __restrict__ O)
{
    const int tid  = threadIdx.x;
    const int wave = tid >> 6;
    const int lane = tid & 63;
    const int blk  = blockIdx.x;
    const int chunk = blk & 7;                 // n-chunk (64 rows)
    const int h     = (blk >> 3) & (H_ - 1);
    const int b     = blk >> 6;

    const int n   = chunk * 64 + lane;
    const int row = b * N_ + n;

    __shared__ float qel[64][NB + 1];          // per-row QE table, padded
    __shared__ float accl[4][64][17];          // per-wave partials: 16 acc + l

    // stage QE: 64 rows x 32 buckets; thread t loads 8 values
    {
        int r = tid >> 2, part = tid & 3;
        const float* src = QE + ((size_t)(b * N_ + chunk * 64 + r) * H_ + h) * NB + part * 8;
#pragma unroll
        for (int j = 0; j < 8; ++j) qel[r][part * 8 + j] = src[j];
    }

    // per-lane query row
    const float4* qp = (const float4*)(Q + (size_t)row * D_ + h * DK);
    const float4 q0 = qp[0], q1 = qp[1], q2 = qp[2], q3 = qp[3];
    const float cx = coords[(size_t)row * 2 + 0];
    const float cy = coords[(size_t)row * 2 + 1];

    __syncthreads();

    const size_t hdbase = (size_t)b * N_ * D_ + h * DK;

    float l = 0.f;
    float acc[16] = {};

    const int m0 = wave * 128;
#pragma unroll 2
    for (int m = m0; m < m0 + 128; ++m) {
        // wave-uniform K row -> scalar loads
        const float4* kp = (const float4*)(K + hdbase + (size_t)m * D_);
        const float4 k0 = kp[0], k1 = kp[1], k2 = kp[2], k3 = kp[3];
        float dot = q0.x*k0.x + q0.y*k0.y + q0.z*k0.z + q0.w*k0.w
                  + q1.x*k1.x + q1.y*k1.y + q1.z*k1.z + q1.w*k1.w
                  + q2.x*k2.x + q2.y*k2.y + q2.z*k2.z + q2.w*k2.w
                  + q3.x*k3.x + q3.y*k3.y + q3.z*k3.z + q3.w*k3.w;
        const float2 cm = *(const float2*)&coords[(size_t)(b * N_ + m) * 2];
        float dx = cx - cm.x, dy = cy - cm.y;
        float dist = sqrtf(dx * dx + dy * dy);
        int bucket = (int)(dist * 32.0f);
        bucket = bucket > (NB - 1) ? (NB - 1) : bucket;
        float s = dot * 0.25f + qel[lane][bucket];
        float p = __expf(s);
        l += p;
        const float4* vp = (const float4*)(V + hdbase + (size_t)m * D_);
        const float4 v0 = vp[0], v1 = vp[1], v2 = vp[2], v3 = vp[3];
        acc[0]  += p * v0.x; acc[1]  += p * v0.y; acc[2]  += p * v0.z; acc[3]  += p * v0.w;
        acc[4]  += p * v1.x; acc[5]  += p * v1.y; acc[6]  += p * v1.z; acc[7]  += p * v1.w;
        acc[8]  += p * v2.x; acc[9]  += p * v2.y; acc[10] += p * v2.z; acc[11] += p * v2.w;
        acc[12] += p * v3.x; acc[13] += p * v3.y; acc[14] += p * v3.z; acc[15] += p * v3.w;
    }

    accl[wave][lane][16] = l;
#pragma unroll
    for (int j = 0; j < 16; ++j) accl[wave][lane][j] = acc[j];
    __syncthreads();

    // combine: 64 rows x 16 dk = 1024 outputs; 256 threads x 4
    {
        int r = tid >> 2, jg = (tid & 3) * 4;
        float lsum = accl[0][r][16] + accl[1][r][16] + accl[2][r][16] + accl[3][r][16];
        float inv = 1.0f / lsum;
        float* op = O + (size_t)(b * N_ + chunk * 64 + r) * D_ + h * DK + jg;
#pragma unroll
        for (int j = 0; j < 4; ++j) {
            float o = accl[0][r][jg + j] + accl[1][r][jg + j]
                    + accl[2][r][jg + j] + accl[3][r][jg + j];
            op[j] = o * inv;
        }
    }
}

// ---------------- instance norm over N per (b,d) ----------------
__global__ __launch_bounds__(512) void inorm_kernel(const float* __restrict__ X,
                                                    const float* __restrict__ gamma,
                                                    const float* __restrict__ beta,
                                                    float* __restrict__ Y)
{
    const int b = blockIdx.x;
    const int t = threadIdx.x;
    const int d = t & (D_ - 1);
    const int s = t >> 7;
    const float* xb = X + (size_t)b * N_ * D_;

    float sum = 0.f, sq = 0.f;
    for (int n = s * 128; n < s * 128 + 128; ++n) {
        float x = xb[(size_t)n * D_ + d];
        sum += x; sq += x * x;
    }
    __shared__ float ls[4][D_], lq[4][D_];
    __shared__ float lm[D_], lr[D_];
    ls[s][d] = sum; lq[s][d] = sq;
    __syncthreads();
    if (s == 0) {
        float S = ls[0][d] + ls[1][d] + ls[2][d] + ls[3][d];
        float Q2 = lq[0][d] + lq[1][d] + lq[2][d] + lq[3][d];
        float mean = S * (1.0f / N_);
        float var = Q2 * (1.0f / N_) - mean * mean;
        lm[d] = mean;
        lr[d] = 1.0f / sqrtf(var + 1e-5f);
    }
    __syncthreads();
    const float mean = lm[d], rstd = lr[d], g = gamma[d], be = beta[d];
    float* yb = Y + (size_t)b * N_ * D_;
    for (int n = s * 128; n < s * 128 + 128; ++n) {
        float x = xb[(size_t)n * D_ + d];
        yb[(size_t)n * D_ + d] = (x - mean) * rstd * g + be;
    }
}

extern "C" void kernel_launch(void* const* d_in, const int* in_sizes, int n_in,
                              void* d_out, int out_size, void* d_ws, size_t ws_size,
                              hipStream_t stream)
{
    const float* h      = (const float*)d_in[0];
    const float* coords = (const float*)d_in[1];
    const float* W_Q    = (const float*)d_in[2];
    const float* W_K    = (const float*)d_in[3];
    const float* W_V    = (const float*)d_in[4];
    const float* W_O    = (const float*)d_in[5];
    const float* emb    = (const float*)d_in[6];
    const float* w1     = (const float*)d_in[7];
    const float* b1     = (const float*)d_in[8];
    const float* w2     = (const float*)d_in[9];
    const float* b2     = (const float*)d_in[10];
    const float* g1     = (const float*)d_in[11];
    const float* be1    = (const float*)d_in[12];
    const float* g2     = (const float*)d_in[13];
    const float* be2    = (const float*)d_in[14];
    float* out = (float*)d_out;

    float* ws = (float*)d_ws;
    const size_t R = (size_t)B_ * N_;          // 2048 rows
    float* Qb  = ws;
    float* Kb  = Qb + R * D_;
    float* Vb  = Kb + R * D_;
    float* QEb = Vb + R * D_;                  // R * H_ * NB
    float* AO  = QEb + R * H_ * NB;
    float* X1  = AO + R * D_;
    float* H1  = X1 + R * D_;
    float* F1  = H1 + R * D_;                  // R * DFF
    float* X2  = F1 + R * DFF;

    // 1. Q,K,V projections (fused via blockIdx.z)
    gemm_kernel<<<dim3(D_ / BN, R / BM, 3), 256, 0, stream>>>(
        h, W_Q, W_K, W_V, Qb, Kb, Vb, nullptr, nullptr, (int)R, D_, D_, 0);
    // 2. QE table (32-bucket factorization of the relative-position einsum)
    qe_kernel<<<dim3((R * H_ * NB) / 256), 256, 0, stream>>>(Qb, emb, QEb);
    // 3. attention v2
    attn2_kernel<<<dim3(B_ * H_ * (N_ / 64)), 256, 0, stream>>>(Qb, Kb, Vb, QEb, coords, AO);
    // 4. O-projection + residual h
    gemm_kernel<<<dim3(D_ / BN, R / BM, 1), 256, 0, stream>>>(
        AO, W_O, W_O, W_O, X1, X1, X1, nullptr, h, (int)R, D_, D_, 0);
    // 5. instance norm 1
    inorm_kernel<<<dim3(B_), 512, 0, stream>>>(X1, g1, be1, H1);
    // 6. FFN layer 1 (+bias, relu)
    gemm_kernel<<<dim3(DFF / BN, R / BM, 1), 256, 0, stream>>>(
        H1, w1, w1, w1, F1, F1, F1, b1, nullptr, (int)R, DFF, D_, 1);
    // 7. FFN layer 2 (+bias, +residual h1)
    gemm_kernel<<<dim3(D_ / BN, R / BM, 1), 256, 0, stream>>>(
        F1, w2, w2, w2, X2, X2, X2, b2, H1, (int)R, D_, DFF, 0);
    // 8. instance norm 2 -> output
    inorm_kernel<<<dim3(B_), 512, 0, stream>>>(X2, g2, be2, out);
}

// Round 3
// 177.630 us; speedup vs baseline: 1.8787x; 1.4094x over previous
//
#include <hip/hip_runtime.h>
#include <hip/hip_bf16.h>

#define B_  4
#define N_  512
#define D_  128
#define H_  8
#define DK  16
#define DFF 512
#define NB  32
#define KS  4            // key-split factor for attention

// ---------------- generic tiled fp32 GEMM ----------------
#define BM 64
#define BN 64
#define BKK 16

__global__ __launch_bounds__(256) void gemm_kernel(
    const float* __restrict__ A,
    const float* __restrict__ B0, const float* __restrict__ B1, const float* __restrict__ B2,
    float* __restrict__ C0, float* __restrict__ C1, float* __restrict__ C2,
    const float* __restrict__ bias, const float* __restrict__ resid,
    int M, int N, int K, int relu)
{
    const float* Bm = blockIdx.z == 0 ? B0 : (blockIdx.z == 1 ? B1 : B2);
    float*       C  = blockIdx.z == 0 ? C0 : (blockIdx.z == 1 ? C1 : C2);

    __shared__ float As[BM][BKK + 1];
    __shared__ float Bs[BKK][BN];

    const int tid = threadIdx.x;
    const int tx = tid & 15, ty = tid >> 4;
    const int bn = blockIdx.x * BN;
    const int bmrow = blockIdx.y * BM;

    const int ar = tid >> 2, ac = (tid & 3) << 2;
    const int br = tid >> 4, bc = (tid & 15) << 2;

    float acc[4][4] = {};

    for (int k0 = 0; k0 < K; k0 += BKK) {
        float4 av = *(const float4*)&A[(size_t)(bmrow + ar) * K + k0 + ac];
        As[ar][ac + 0] = av.x; As[ar][ac + 1] = av.y;
        As[ar][ac + 2] = av.z; As[ar][ac + 3] = av.w;
        float4 bv = *(const float4*)&Bm[(size_t)(k0 + br) * N + bn + bc];
        *(float4*)&Bs[br][bc] = bv;
        __syncthreads();
#pragma unroll
        for (int kk = 0; kk < BKK; ++kk) {
            float a0 = As[ty * 4 + 0][kk];
            float a1 = As[ty * 4 + 1][kk];
            float a2 = As[ty * 4 + 2][kk];
            float a3 = As[ty * 4 + 3][kk];
            float4 b = *(float4*)&Bs[kk][tx * 4];
            acc[0][0] += a0 * b.x; acc[0][1] += a0 * b.y; acc[0][2] += a0 * b.z; acc[0][3] += a0 * b.w;
            acc[1][0] += a1 * b.x; acc[1][1] += a1 * b.y; acc[1][2] += a1 * b.z; acc[1][3] += a1 * b.w;
            acc[2][0] += a2 * b.x; acc[2][1] += a2 * b.y; acc[2][2] += a2 * b.z; acc[2][3] += a2 * b.w;
            acc[3][0] += a3 * b.x; acc[3][1] += a3 * b.y; acc[3][2] += a3 * b.z; acc[3][3] += a3 * b.w;
        }
        __syncthreads();
    }

    float4 bb = make_float4(0.f, 0.f, 0.f, 0.f);
    if (bias) bb = *(const float4*)&bias[bn + tx * 4];
#pragma unroll
    for (int i = 0; i < 4; ++i) {
        int row = bmrow + ty * 4 + i;
        float4 r;
        r.x = acc[i][0] + bb.x; r.y = acc[i][1] + bb.y;
        r.z = acc[i][2] + bb.z; r.w = acc[i][3] + bb.w;
        if (resid) {
            float4 rv = *(const float4*)&resid[(size_t)row * N + bn + tx * 4];
            r.x += rv.x; r.y += rv.y; r.z += rv.z; r.w += rv.w;
        }
        if (relu) {
            r.x = fmaxf(r.x, 0.f); r.y = fmaxf(r.y, 0.f);
            r.z = fmaxf(r.z, 0.f); r.w = fmaxf(r.w, 0.f);
        }
        *(float4*)&C[(size_t)row * N + bn + tx * 4] = r;
    }
}

// ---------------- QE precompute: QE[row,h,k] = Q[row,h,:] . emb[k,h,:] ----------------
__global__ __launch_bounds__(256) void qe_kernel(const float* __restrict__ Q,
                                                 const float* __restrict__ emb,
                                                 float* __restrict__ QE)
{
    int idx = blockIdx.x * 256 + threadIdx.x;   // [0, R*H*NB)
    int k   = idx & (NB - 1);
    int hh  = (idx >> 5) & (H_ - 1);
    int row = idx >> 8;
    const float4* qp = (const float4*)(Q + (size_t)row * D_ + hh * DK);
    const float4* ep = (const float4*)(emb + (size_t)k * D_ + hh * DK);
    float4 q0 = qp[0], q1 = qp[1], q2 = qp[2], q3 = qp[3];
    float4 e0 = ep[0], e1 = ep[1], e2 = ep[2], e3 = ep[3];
    float dot = q0.x*e0.x + q0.y*e0.y + q0.z*e0.z + q0.w*e0.w
              + q1.x*e1.x + q1.y*e1.y + q1.z*e1.z + q1.w*e1.w
              + q2.x*e2.x + q2.y*e2.y + q2.z*e2.z + q2.w*e2.w
              + q3.x*e3.x + q3.y*e3.y + q3.z*e3.z + q3.w*e3.w;
    QE[idx] = dot;
}

// ---------------- attention v3: lane-per-query-row, key-split across blocks -------
// grid = B*H*8chunks*KS = 1024 blocks (4/CU, 16 waves/CU = 50% occupancy).
// Block (b,h,chunk,ks): 64 query rows (one per lane), keys [ks*128, ks*128+128).
// Wave w covers 32 keys. K/V row addresses are made provably wave-uniform via
// readfirstlane -> scalar loads. Partial (16 acc + l) per block -> ws; combine
// kernel sums KS slices and normalizes. exp without max-subtract (|s| <~ 12).
__global__ __launch_bounds__(256) void attn3_kernel(
    const float* __restrict__ Q, const float* __restrict__ K, const float* __restrict__ V,
    const float* __restrict__ QE, const float* __restrict__ coords,
    float* __restrict__ P)
{
    const int tid  = threadIdx.x;
    const int wave = tid >> 6;
    const int lane = tid & 63;
    const int bid  = blockIdx.x;
    const int ks    = bid & (KS - 1);
    const int chunk = (bid >> 2) & 7;
    const int h     = (bid >> 5) & (H_ - 1);
    const int b     = bid >> 8;

    const int n   = chunk * 64 + lane;
    const int row = b * N_ + n;

    __shared__ float qel[64][NB + 1];          // per-row QE table, padded
    __shared__ float ckrd[128][2];             // key coords for this slice
    __shared__ float accl[4][64][17];          // per-wave partials: 16 acc + l

    // stage QE: 64 rows x 32 buckets
    {
        int r = tid >> 2, part = tid & 3;
        const float* src = QE + ((size_t)(b * N_ + chunk * 64 + r) * H_ + h) * NB + part * 8;
#pragma unroll
        for (int j = 0; j < 8; ++j) qel[r][part * 8 + j] = src[j];
    }
    // stage key coords: 128 keys x 2 floats = 256 loads
    ((float*)ckrd)[tid] = coords[(size_t)(b * N_ + ks * 128) * 2 + tid];

    // per-lane query row
    const float4* qp = (const float4*)(Q + (size_t)row * D_ + h * DK);
    const float4 q0 = qp[0], q1 = qp[1], q2 = qp[2], q3 = qp[3];
    const float cx = coords[(size_t)row * 2 + 0];
    const float cy = coords[(size_t)row * 2 + 1];

    __syncthreads();

    const size_t hdbase = (size_t)b * N_ * D_ + h * DK;

    float l = 0.f;
    float acc[16] = {};

    // force wave-uniformity so the compiler can scalarize K/V loads
    const int m0 = __builtin_amdgcn_readfirstlane(ks * 128 + wave * 32);
#pragma unroll 4
    for (int i = 0; i < 32; ++i) {
        const int m = m0 + i;
        const float4* kp = (const float4*)(K + hdbase + (size_t)m * D_);
        const float4 k0 = kp[0], k1 = kp[1], k2 = kp[2], k3 = kp[3];
        float dot = q0.x*k0.x + q0.y*k0.y + q0.z*k0.z + q0.w*k0.w
                  + q1.x*k1.x + q1.y*k1.y + q1.z*k1.z + q1.w*k1.w
                  + q2.x*k2.x + q2.y*k2.y + q2.z*k2.z + q2.w*k2.w
                  + q3.x*k3.x + q3.y*k3.y + q3.z*k3.z + q3.w*k3.w;
        const int mloc = m - ks * 128;
        float dx = cx - ckrd[mloc][0], dy = cy - ckrd[mloc][1];
        float dist = sqrtf(dx * dx + dy * dy);
        int bucket = (int)(dist * 32.0f);
        bucket = bucket > (NB - 1) ? (NB - 1) : bucket;
        float s = dot * 0.25f + qel[lane][bucket];
        float p = __expf(s);
        l += p;
        const float4* vp = (const float4*)(V + hdbase + (size_t)m * D_);
        const float4 v0 = vp[0], v1 = vp[1], v2 = vp[2], v3 = vp[3];
        acc[0]  += p * v0.x; acc[1]  += p * v0.y; acc[2]  += p * v0.z; acc[3]  += p * v0.w;
        acc[4]  += p * v1.x; acc[5]  += p * v1.y; acc[6]  += p * v1.z; acc[7]  += p * v1.w;
        acc[8]  += p * v2.x; acc[9]  += p * v2.y; acc[10] += p * v2.z; acc[11] += p * v2.w;
        acc[12] += p * v3.x; acc[13] += p * v3.y; acc[14] += p * v3.z; acc[15] += p * v3.w;
    }

    accl[wave][lane][16] = l;
#pragma unroll
    for (int j = 0; j < 16; ++j) accl[wave][lane][j] = acc[j];
    __syncthreads();

    // reduce the 4 waves and write one partial record per block: P[bid][64][17]
    float* pb = P + (size_t)bid * (64 * 17);
    for (int i = tid; i < 64 * 17; i += 256) {
        int r = i / 17, j = i - r * 17;
        pb[i] = accl[0][r][j] + accl[1][r][j] + accl[2][r][j] + accl[3][r][j];
    }
}

// combine KS partial slices -> normalized attention output AO[row][h*16+dk]
__global__ __launch_bounds__(256) void attn3_combine_kernel(
    const float* __restrict__ P, float* __restrict__ AO)
{
    int idx = blockIdx.x * 256 + threadIdx.x;   // [0, R*D)
    int d  = idx & (D_ - 1);
    int r  = idx >> 7;                          // global row
    int h  = d >> 4, dk = d & 15;
    int b  = r >> 9, n = r & (N_ - 1);
    int chunk = n >> 6, rl = n & 63;
    size_t base = ((size_t)(((b * H_ + h) * 8 + chunk) * KS)) * (64 * 17) + (size_t)rl * 17;
    float a = 0.f, l = 0.f;
#pragma unroll
    for (int s = 0; s < KS; ++s) {
        const float* ps = P + base + (size_t)s * (64 * 17);
        a += ps[dk];
        l += ps[16];
    }
    AO[idx] = a / l;
}

// ---------------- instance norm over N per (b,d) ----------------
__global__ __launch_bounds__(512) void inorm_kernel(const float* __restrict__ X,
                                                    const float* __restrict__ gamma,
                                                    const float* __restrict__ beta,
                                                    float* __restrict__ Y)
{
    const int b = blockIdx.x;
    const int t = threadIdx.x;
    const int d = t & (D_ - 1);
    const int s = t >> 7;
    const float* xb = X + (size_t)b * N_ * D_;

    float sum = 0.f, sq = 0.f;
    for (int n = s * 128; n < s * 128 + 128; ++n) {
        float x = xb[(size_t)n * D_ + d];
        sum += x; sq += x * x;
    }
    __shared__ float ls[4][D_], lq[4][D_];
    __shared__ float lm[D_], lr[D_];
    ls[s][d] = sum; lq[s][d] = sq;
    __syncthreads();
    if (s == 0) {
        float S = ls[0][d] + ls[1][d] + ls[2][d] + ls[3][d];
        float Q2 = lq[0][d] + lq[1][d] + lq[2][d] + lq[3][d];
        float mean = S * (1.0f / N_);
        float var = Q2 * (1.0f / N_) - mean * mean;
        lm[d] = mean;
        lr[d] = 1.0f / sqrtf(var + 1e-5f);
    }
    __syncthreads();
    const float mean = lm[d], rstd = lr[d], g = gamma[d], be = beta[d];
    float* yb = Y + (size_t)b * N_ * D_;
    for (int n = s * 128; n < s * 128 + 128; ++n) {
        float x = xb[(size_t)n * D_ + d];
        yb[(size_t)n * D_ + d] = (x - mean) * rstd * g + be;
    }
}

extern "C" void kernel_launch(void* const* d_in, const int* in_sizes, int n_in,
                              void* d_out, int out_size, void* d_ws, size_t ws_size,
                              hipStream_t stream)
{
    const float* h      = (const float*)d_in[0];
    const float* coords = (const float*)d_in[1];
    const float* W_Q    = (const float*)d_in[2];
    const float* W_K    = (const float*)d_in[3];
    const float* W_V    = (const float*)d_in[4];
    const float* W_O    = (const float*)d_in[5];
    const float* emb    = (const float*)d_in[6];
    const float* w1     = (const float*)d_in[7];
    const float* b1     = (const float*)d_in[8];
    const float* w2     = (const float*)d_in[9];
    const float* b2     = (const float*)d_in[10];
    const float* g1     = (const float*)d_in[11];
    const float* be1    = (const float*)d_in[12];
    const float* g2     = (const float*)d_in[13];
    const float* be2    = (const float*)d_in[14];
    float* out = (float*)d_out;

    float* ws = (float*)d_ws;
    const size_t R = (size_t)B_ * N_;          // 2048 rows
    float* Qb  = ws;
    float* Kb  = Qb + R * D_;
    float* Vb  = Kb + R * D_;
    float* QEb = Vb + R * D_;                  // R * H_ * NB
    float* AO  = QEb + R * H_ * NB;
    float* X1  = AO + R * D_;
    float* H1  = X1 + R * D_;
    float* F1  = H1 + R * D_;                  // R * DFF
    float* X2  = F1 + R * DFF;
    float* Pb  = X2 + R * D_;                  // 1024 * 64 * 17 partials

    // 1. Q,K,V projections (fused via blockIdx.z)
    gemm_kernel<<<dim3(D_ / BN, R / BM, 3), 256, 0, stream>>>(
        h, W_Q, W_K, W_V, Qb, Kb, Vb, nullptr, nullptr, (int)R, D_, D_, 0);
    // 2. QE table (32-bucket factorization of the relative-position einsum)
    qe_kernel<<<dim3((R * H_ * NB) / 256), 256, 0, stream>>>(Qb, emb, QEb);
    // 3. attention v3 (key-split) + combine
    attn3_kernel<<<dim3(B_ * H_ * 8 * KS), 256, 0, stream>>>(Qb, Kb, Vb, QEb, coords, Pb);
    attn3_combine_kernel<<<dim3((R * D_) / 256), 256, 0, stream>>>(Pb, AO);
    // 4. O-projection + residual h
    gemm_kernel<<<dim3(D_ / BN, R / BM, 1), 256, 0, stream>>>(
        AO, W_O, W_O, W_O, X1, X1, X1, nullptr, h, (int)R, D_, D_, 0);
    // 5. instance norm 1
    inorm_kernel<<<dim3(B_), 512, 0, stream>>>(X1, g1, be1, H1);
    // 6. FFN layer 1 (+bias, relu)
    gemm_kernel<<<dim3(DFF / BN, R / BM, 1), 256, 0, stream>>>(
        H1, w1, w1, w1, F1, F1, F1, b1, nullptr, (int)R, DFF, D_, 1);
    // 7. FFN layer 2 (+bias, +residual h1)
    gemm_kernel<<<dim3(D_ / BN, R / BM, 1), 256, 0, stream>>>(
        F1, w2, w2, w2, X2, X2, X2, b2, H1, (int)R, D_, DFF, 0);
    // 8. instance norm 2 -> output
    inorm_kernel<<<dim3(B_), 512, 0, stream>>>(X2, g2, be2, out);
}

// Round 4
// 105.842 us; speedup vs baseline: 3.1530x; 1.6783x over previous
//
#include <hip/hip_runtime.h>
#include <hip/hip_bf16.h>

#define B_  4
#define N_  512
#define D_  128
#define H_  8
#define DK  16
#define DFF 512
#define NB  32
#define KS  4            // key-split factor for attention

// ---------------- GEMV-style skinny GEMM ----------------
// C = A[M,K] @ B[K,N] (+bias) (+resid) (relu). Wave owns ROWS=4 rows; lanes span
// all N columns (NC = N/64 per lane). A loads are wave-uniform (scalar), B loads
// coalesced and L1/L2-hot. No LDS, no barriers. blockIdx.z selects B/C pair.
template <int N, int K, int RELU>
__global__ __launch_bounds__(256) void gemv_kernel(
    const float* __restrict__ A,
    const float* __restrict__ B0, const float* __restrict__ B1, const float* __restrict__ B2,
    float* __restrict__ C0, float* __restrict__ C1, float* __restrict__ C2,
    const float* __restrict__ bias, const float* __restrict__ resid)
{
    constexpr int NC = N / 64;
    constexpr int ROWS = 4;
    const float* Bw = blockIdx.z == 0 ? B0 : (blockIdx.z == 1 ? B1 : B2);
    float*       C  = blockIdx.z == 0 ? C0 : (blockIdx.z == 1 ? C1 : C2);
    const int wave = threadIdx.x >> 6;
    const int lane = threadIdx.x & 63;
    const int rbase = __builtin_amdgcn_readfirstlane((blockIdx.x * 4 + wave) * ROWS);
    const int col = lane * NC;

    float acc[ROWS][NC] = {};

    for (int k0 = 0; k0 < K; k0 += 4) {
        float4 a4[ROWS];
#pragma unroll
        for (int j = 0; j < ROWS; ++j)
            a4[j] = *(const float4*)&A[(size_t)(rbase + j) * K + k0];
#pragma unroll
        for (int kk = 0; kk < 4; ++kk) {
            const float* brow = &Bw[(size_t)(k0 + kk) * N + col];
            float bv[NC];
            if constexpr (NC == 2) {
                float2 t = *(const float2*)brow; bv[0] = t.x; bv[1] = t.y;
            } else {
#pragma unroll
                for (int c = 0; c < NC; c += 4) {
                    float4 t = *(const float4*)&brow[c];
                    bv[c] = t.x; bv[c + 1] = t.y; bv[c + 2] = t.z; bv[c + 3] = t.w;
                }
            }
#pragma unroll
            for (int j = 0; j < ROWS; ++j) {
                float a = (&a4[j].x)[kk];
#pragma unroll
                for (int c = 0; c < NC; ++c) acc[j][c] += a * bv[c];
            }
        }
    }

    float bb[NC];
#pragma unroll
    for (int c = 0; c < NC; ++c) bb[c] = bias ? bias[col + c] : 0.f;

#pragma unroll
    for (int j = 0; j < ROWS; ++j) {
        const int row = rbase + j;
        float o[NC];
#pragma unroll
        for (int c = 0; c < NC; ++c) o[c] = acc[j][c] + bb[c];
        if (resid) {
            if constexpr (NC == 2) {
                float2 rv = *(const float2*)&resid[(size_t)row * N + col];
                o[0] += rv.x; o[1] += rv.y;
            } else {
#pragma unroll
                for (int c = 0; c < NC; c += 4) {
                    float4 rv = *(const float4*)&resid[(size_t)row * N + col + c];
                    o[c] += rv.x; o[c + 1] += rv.y; o[c + 2] += rv.z; o[c + 3] += rv.w;
                }
            }
        }
        if (RELU) {
#pragma unroll
            for (int c = 0; c < NC; ++c) o[c] = fmaxf(o[c], 0.f);
        }
        if constexpr (NC == 2) {
            *(float2*)&C[(size_t)row * N + col] = make_float2(o[0], o[1]);
        } else {
#pragma unroll
            for (int c = 0; c < NC; c += 4)
                *(float4*)&C[(size_t)row * N + col + c] = make_float4(o[c], o[c+1], o[c+2], o[c+3]);
        }
    }
}

// ---------------- QE precompute: QE[row,h,k] = Q[row,h,:] . emb[k,h,:] ----------------
__global__ __launch_bounds__(256) void qe_kernel(const float* __restrict__ Q,
                                                 const float* __restrict__ emb,
                                                 float* __restrict__ QE)
{
    int idx = blockIdx.x * 256 + threadIdx.x;   // [0, R*H*NB)
    int k   = idx & (NB - 1);
    int hh  = (idx >> 5) & (H_ - 1);
    int row = idx >> 8;
    const float4* qp = (const float4*)(Q + (size_t)row * D_ + hh * DK);
    const float4* ep = (const float4*)(emb + (size_t)k * D_ + hh * DK);
    float4 q0 = qp[0], q1 = qp[1], q2 = qp[2], q3 = qp[3];
    float4 e0 = ep[0], e1 = ep[1], e2 = ep[2], e3 = ep[3];
    float dot = q0.x*e0.x + q0.y*e0.y + q0.z*e0.z + q0.w*e0.w
              + q1.x*e1.x + q1.y*e1.y + q1.z*e1.z + q1.w*e1.w
              + q2.x*e2.x + q2.y*e2.y + q2.z*e2.z + q2.w*e2.w
              + q3.x*e3.x + q3.y*e3.y + q3.z*e3.z + q3.w*e3.w;
    QE[idx] = dot;
}

// ---------------- attention v3: lane-per-query-row, key-split across blocks -------
__global__ __launch_bounds__(256) void attn3_kernel(
    const float* __restrict__ Q, const float* __restrict__ K, const float* __restrict__ V,
    const float* __restrict__ QE, const float* __restrict__ coords,
    float* __restrict__ P)
{
    const int tid  = threadIdx.x;
    const int wave = tid >> 6;
    const int lane = tid & 63;
    const int bid  = blockIdx.x;
    const int ks    = bid & (KS - 1);
    const int chunk = (bid >> 2) & 7;
    const int h     = (bid >> 5) & (H_ - 1);
    const int b     = bid >> 8;

    const int n   = chunk * 64 + lane;
    const int row = b * N_ + n;

    __shared__ float qel[64][NB + 1];
    __shared__ float ckrd[128][2];
    __shared__ float accl[4][64][17];

    {
        int r = tid >> 2, part = tid & 3;
        const float* src = QE + ((size_t)(b * N_ + chunk * 64 + r) * H_ + h) * NB + part * 8;
#pragma unroll
        for (int j = 0; j < 8; ++j) qel[r][part * 8 + j] = src[j];
    }
    ((float*)ckrd)[tid] = coords[(size_t)(b * N_ + ks * 128) * 2 + tid];

    const float4* qp = (const float4*)(Q + (size_t)row * D_ + h * DK);
    const float4 q0 = qp[0], q1 = qp[1], q2 = qp[2], q3 = qp[3];
    const float cx = coords[(size_t)row * 2 + 0];
    const float cy = coords[(size_t)row * 2 + 1];

    __syncthreads();

    const size_t hdbase = (size_t)b * N_ * D_ + h * DK;

    float l = 0.f;
    float acc[16] = {};

    const int m0 = __builtin_amdgcn_readfirstlane(ks * 128 + wave * 32);
#pragma unroll 4
    for (int i = 0; i < 32; ++i) {
        const int m = m0 + i;
        const float4* kp = (const float4*)(K + hdbase + (size_t)m * D_);
        const float4 k0 = kp[0], k1 = kp[1], k2 = kp[2], k3 = kp[3];
        float dot = q0.x*k0.x + q0.y*k0.y + q0.z*k0.z + q0.w*k0.w
                  + q1.x*k1.x + q1.y*k1.y + q1.z*k1.z + q1.w*k1.w
                  + q2.x*k2.x + q2.y*k2.y + q2.z*k2.z + q2.w*k2.w
                  + q3.x*k3.x + q3.y*k3.y + q3.z*k3.z + q3.w*k3.w;
        const int mloc = m - ks * 128;
        float dx = cx - ckrd[mloc][0], dy = cy - ckrd[mloc][1];
        float dist = sqrtf(dx * dx + dy * dy);
        int bucket = (int)(dist * 32.0f);
        bucket = bucket > (NB - 1) ? (NB - 1) : bucket;
        float s = dot * 0.25f + qel[lane][bucket];
        float p = __expf(s);
        l += p;
        const float4* vp = (const float4*)(V + hdbase + (size_t)m * D_);
        const float4 v0 = vp[0], v1 = vp[1], v2 = vp[2], v3 = vp[3];
        acc[0]  += p * v0.x; acc[1]  += p * v0.y; acc[2]  += p * v0.z; acc[3]  += p * v0.w;
        acc[4]  += p * v1.x; acc[5]  += p * v1.y; acc[6]  += p * v1.z; acc[7]  += p * v1.w;
        acc[8]  += p * v2.x; acc[9]  += p * v2.y; acc[10] += p * v2.z; acc[11] += p * v2.w;
        acc[12] += p * v3.x; acc[13] += p * v3.y; acc[14] += p * v3.z; acc[15] += p * v3.w;
    }

    accl[wave][lane][16] = l;
#pragma unroll
    for (int j = 0; j < 16; ++j) accl[wave][lane][j] = acc[j];
    __syncthreads();

    float* pb = P + (size_t)bid * (64 * 17);
    for (int i = tid; i < 64 * 17; i += 256) {
        int r = i / 17, j = i - r * 17;
        pb[i] = accl[0][r][j] + accl[1][r][j] + accl[2][r][j] + accl[3][r][j];
    }
}

__global__ __launch_bounds__(256) void attn3_combine_kernel(
    const float* __restrict__ P, float* __restrict__ AO)
{
    int idx = blockIdx.x * 256 + threadIdx.x;   // [0, R*D)
    int d  = idx & (D_ - 1);
    int r  = idx >> 7;
    int h  = d >> 4, dk = d & 15;
    int b  = r >> 9, n = r & (N_ - 1);
    int chunk = n >> 6, rl = n & 63;
    size_t base = ((size_t)(((b * H_ + h) * 8 + chunk) * KS)) * (64 * 17) + (size_t)rl * 17;
    float a = 0.f, l = 0.f;
#pragma unroll
    for (int s = 0; s < KS; ++s) {
        const float* ps = P + base + (size_t)s * (64 * 17);
        a += ps[dk];
        l += ps[16];
    }
    AO[idx] = a / l;
}

// ---------------- instance norm: stats (mean/rstd per (b,d)) + apply --------------
__global__ __launch_bounds__(256) void inorm_stats_kernel(const float* __restrict__ X,
                                                          float* __restrict__ Mo,
                                                          float* __restrict__ Ro)
{
    // grid = B*8; block handles (b, group of 16 d's)
    const int b  = blockIdx.x >> 3;
    const int dg = blockIdx.x & 7;
    const int dl = threadIdx.x & 15;
    const int nc = threadIdx.x >> 4;        // 16 n-chunks of 32
    const int d  = dg * 16 + dl;
    const float* xb = X + (size_t)b * N_ * D_ + d;
    float s = 0.f, q = 0.f;
    for (int i = 0; i < 32; ++i) {
        float x = xb[(size_t)(nc * 32 + i) * D_];
        s += x; q += x * x;
    }
    __shared__ float ls[16][17], lq[16][17];
    ls[nc][dl] = s; lq[nc][dl] = q;
    __syncthreads();
    if (threadIdx.x < 16) {
        float S = 0.f, Q2 = 0.f;
#pragma unroll
        for (int i = 0; i < 16; ++i) { S += ls[i][threadIdx.x]; Q2 += lq[i][threadIdx.x]; }
        float mean = S * (1.0f / N_);
        float var  = Q2 * (1.0f / N_) - mean * mean;
        Mo[b * D_ + dg * 16 + threadIdx.x] = mean;
        Ro[b * D_ + dg * 16 + threadIdx.x] = 1.0f / sqrtf(var + 1e-5f);
    }
}

__global__ __launch_bounds__(256) void inorm_apply_kernel(const float* __restrict__ X,
    const float* __restrict__ Mo, const float* __restrict__ Ro,
    const float* __restrict__ gamma, const float* __restrict__ beta,
    float* __restrict__ Y)
{
    int idx = (blockIdx.x * 256 + threadIdx.x) * 4;   // float4-aligned element index
    int d = idx & (D_ - 1);
    int b = idx >> 16;                                 // / (N_*D_) = 65536
    float4 x  = *(const float4*)&X[idx];
    float4 m  = *(const float4*)&Mo[b * D_ + d];
    float4 r  = *(const float4*)&Ro[b * D_ + d];
    float4 g  = *(const float4*)&gamma[d];
    float4 be = *(const float4*)&beta[d];
    float4 y;
    y.x = (x.x - m.x) * r.x * g.x + be.x;
    y.y = (x.y - m.y) * r.y * g.y + be.y;
    y.z = (x.z - m.z) * r.z * g.z + be.z;
    y.w = (x.w - m.w) * r.w * g.w + be.w;
    *(float4*)&Y[idx] = y;
}

extern "C" void kernel_launch(void* const* d_in, const int* in_sizes, int n_in,
                              void* d_out, int out_size, void* d_ws, size_t ws_size,
                              hipStream_t stream)
{
    const float* h      = (const float*)d_in[0];
    const float* coords = (const float*)d_in[1];
    const float* W_Q    = (const float*)d_in[2];
    const float* W_K    = (const float*)d_in[3];
    const float* W_V    = (const float*)d_in[4];
    const float* W_O    = (const float*)d_in[5];
    const float* emb    = (const float*)d_in[6];
    const float* w1     = (const float*)d_in[7];
    const float* b1     = (const float*)d_in[8];
    const float* w2     = (const float*)d_in[9];
    const float* b2     = (const float*)d_in[10];
    const float* g1     = (const float*)d_in[11];
    const float* be1    = (const float*)d_in[12];
    const float* g2     = (const float*)d_in[13];
    const float* be2    = (const float*)d_in[14];
    float* out = (float*)d_out;

    float* ws = (float*)d_ws;
    const size_t R = (size_t)B_ * N_;          // 2048 rows
    float* Qb  = ws;
    float* Kb  = Qb + R * D_;
    float* Vb  = Kb + R * D_;
    float* QEb = Vb + R * D_;                  // R * H_ * NB
    float* AO  = QEb + R * H_ * NB;
    float* X1  = AO + R * D_;
    float* H1  = X1 + R * D_;
    float* F1  = H1 + R * D_;                  // R * DFF
    float* X2  = F1 + R * DFF;
    float* Pb  = X2 + R * D_;                  // 1024 * 64 * 17 partials
    float* M1  = Pb + (size_t)1024 * 64 * 17;  // B*D stats
    float* R1  = M1 + B_ * D_;
    float* M2  = R1 + B_ * D_;
    float* R2  = M2 + B_ * D_;

    const int RG = (int)R / 16;                // row-groups per GEMV grid = 128

    // 1. Q,K,V projections (fused via blockIdx.z)
    gemv_kernel<128, 128, 0><<<dim3(RG, 1, 3), 256, 0, stream>>>(
        h, W_Q, W_K, W_V, Qb, Kb, Vb, nullptr, nullptr);
    // 2. QE table (32-bucket factorization of the relative-position einsum)
    qe_kernel<<<dim3((R * H_ * NB) / 256), 256, 0, stream>>>(Qb, emb, QEb);
    // 3. attention v3 (key-split) + combine
    attn3_kernel<<<dim3(B_ * H_ * 8 * KS), 256, 0, stream>>>(Qb, Kb, Vb, QEb, coords, Pb);
    attn3_combine_kernel<<<dim3((R * D_) / 256), 256, 0, stream>>>(Pb, AO);
    // 4. O-projection + residual h
    gemv_kernel<128, 128, 0><<<dim3(RG, 1, 1), 256, 0, stream>>>(
        AO, W_O, W_O, W_O, X1, X1, X1, nullptr, h);
    // 5. instance norm 1 -> H1
    inorm_stats_kernel<<<dim3(B_ * 8), 256, 0, stream>>>(X1, M1, R1);
    inorm_apply_kernel<<<dim3((R * D_) / 1024), 256, 0, stream>>>(X1, M1, R1, g1, be1, H1);
    // 6. FFN layer 1 (+bias, relu)
    gemv_kernel<512, 128, 1><<<dim3(RG, 1, 1), 256, 0, stream>>>(
        H1, w1, w1, w1, F1, F1, F1, b1, nullptr);
    // 7. FFN layer 2 (+bias, +residual H1)
    gemv_kernel<128, 512, 0><<<dim3(RG, 1, 1), 256, 0, stream>>>(
        F1, w2, w2, w2, X2, X2, X2, b2, H1);
    // 8. instance norm 2 -> output
    inorm_stats_kernel<<<dim3(B_ * 8), 256, 0, stream>>>(X2, M2, R2);
    inorm_apply_kernel<<<dim3((R * D_) / 1024), 256, 0, stream>>>(X2, M2, R2, g2, be2, out);
}